// Round 3
// baseline (441.182 us; speedup 1.0000x reference)
//
#include <hip/hip_runtime.h>
#include <stdint.h>

// GAT 3-layer + linear head, MI355X (gfx950).
// I/O is FP32 (per reference). Internals: bf16 MFMA for h and att@h
// (softmax-averaging damps bf16 rounding); logits and final linear in fp32.

typedef unsigned short u16;
typedef __bf16 bf16x8 __attribute__((ext_vector_type(8)));
typedef float f32x4 __attribute__((ext_vector_type(4)));
typedef u16 u16x8 __attribute__((ext_vector_type(8)));

#define LOG2E 1.44269504088896340736f

__device__ __forceinline__ float b2f(u16 u) {
    union { unsigned int i; float f; } v; v.i = ((unsigned int)u) << 16; return v.f;
}
__device__ __forceinline__ u16 f2b(float f) {   // RNE round to bf16
    union { float f; unsigned int i; } v; v.f = f;
    unsigned int i = v.i;
    return (u16)((i + 0x7fffu + ((i >> 16) & 1u)) >> 16);
}

union ABfrag { bf16x8 v; u16x8 u; };

__device__ __forceinline__ void gload_lds16(const u16* g, u16* l) {
    // async global->LDS, 16B/lane, LDS dest = wave-uniform base + lane*16
    __builtin_amdgcn_global_load_lds((const __attribute__((address_space(1))) void*)g,
                                     (__attribute__((address_space(3))) void*)l,
                                     16, 0, 0);
}

// ---------------- prep: bf16-transpose W's, u = (W @ a)*log2e (fp32), zero outf
__global__ void k_prep(const float* __restrict__ W1, const float* __restrict__ W2,
                       const float* __restrict__ W3,
                       const float* __restrict__ a1s, const float* __restrict__ a1d,
                       const float* __restrict__ a2s, const float* __restrict__ a2d,
                       const float* __restrict__ a3s, const float* __restrict__ a3d,
                       u16* __restrict__ Wt1, u16* __restrict__ Wt2, u16* __restrict__ Wt3,
                       float* __restrict__ u1s, float* __restrict__ u1d,
                       float* __restrict__ u2s, float* __restrict__ u2d,
                       float* __restrict__ u3s, float* __restrict__ u3d,
                       float* __restrict__ outf) {
    if (blockIdx.x == 160) {                 // u-vectors: fp32 matvecs, trivial size
        int f = threadIdx.x;
        if (f < 128) {
            float s1 = 0.f, d1 = 0.f, s2 = 0.f, d2 = 0.f, s3 = 0.f, d3 = 0.f;
            for (int o = 0; o < 128; ++o) { float w = W1[f * 128 + o]; s1 += w * a1s[o]; d1 += w * a1d[o]; }
            for (int o = 0; o < 128; ++o) { float w = W2[f * 128 + o]; s2 += w * a2s[o]; d2 += w * a2d[o]; }
            for (int o = 0; o <  64; ++o) { float w = W3[f *  64 + o]; s3 += w * a3s[o]; d3 += w * a3d[o]; }
            u1s[f] = s1 * LOG2E; u1d[f] = d1 * LOG2E;
            u2s[f] = s2 * LOG2E; u2d[f] = d2 * LOG2E;
            u3s[f] = s3 * LOG2E; u3d[f] = d3 * LOG2E;
        }
        return;
    }
    int idx = blockIdx.x * 256 + threadIdx.x;
    if (idx < 1024) outf[idx] = 0.0f;
    if (idx < 16384) {                       // W1: [128,128] -> Wt1[o][f] bf16
        int f = idx >> 7, o = idx & 127;
        Wt1[o * 128 + f] = f2b(W1[idx]);
    } else if (idx < 32768) {                // W2
        int j = idx - 16384; int f = j >> 7, o = j & 127;
        Wt2[o * 128 + f] = f2b(W2[j]);
    } else if (idx < 40960) {                // W3: [128,64] -> Wt3[o][f]
        int j = idx - 32768; int f = j >> 6, o = j & 63;
        Wt3[o * 128 + f] = f2b(W3[j]);
    }
}

// ---------------- k_h: h = act @ W (bf16 MFMA) -> h^T bf16; es/ed = act . u (fp32)
// grid (8, 32) = (b, nblk), block 256 (4 waves x 16 rows). K = 128 always.
template <int F, bool XF32>
__global__ void __launch_bounds__(256) k_h(const void* __restrict__ xv,
                                           const u16* __restrict__ Wt,
                                           const float* __restrict__ us,
                                           const float* __restrict__ ud,
                                           u16* __restrict__ h_t,
                                           float* __restrict__ es2,
                                           float* __restrict__ ed2) {
    constexpr int NT = F / 16;
    constexpr int TNP = 72;                  // padded n-stride (144B = 9x16B)
    __shared__ __align__(16) u16 hl[F * TNP];

    const int b = blockIdx.x;
    const int nblk = blockIdx.y;
    const int tid = threadIdx.x;
    const int w = tid >> 6, lane = tid & 63;
    const int quad = lane >> 4, l15 = lane & 15;
    const int n0w = nblk * 64 + w * 16;
    const int i_a = n0w + l15;               // A-operand row (m = lane&15)

    ABfrag afr[4];
    float ps = 0.f, pd = 0.f;
    if (XF32) {
        const float* xr = (const float*)xv + ((size_t)(b * 2048 + i_a)) * 128;
#pragma unroll
        for (int kk = 0; kk < 4; ++kk) {
            const int o8 = kk * 32 + quad * 8;
            float4 x0 = *reinterpret_cast<const float4*>(xr + o8);
            float4 x1 = *reinterpret_cast<const float4*>(xr + o8 + 4);
            float4 s0 = *reinterpret_cast<const float4*>(us + o8);
            float4 s1 = *reinterpret_cast<const float4*>(us + o8 + 4);
            float4 d0 = *reinterpret_cast<const float4*>(ud + o8);
            float4 d1 = *reinterpret_cast<const float4*>(ud + o8 + 4);
            ps += x0.x * s0.x + x0.y * s0.y + x0.z * s0.z + x0.w * s0.w
                + x1.x * s1.x + x1.y * s1.y + x1.z * s1.z + x1.w * s1.w;
            pd += x0.x * d0.x + x0.y * d0.y + x0.z * d0.z + x0.w * d0.w
                + x1.x * d1.x + x1.y * d1.y + x1.z * d1.z + x1.w * d1.w;
            afr[kk].u[0] = f2b(x0.x); afr[kk].u[1] = f2b(x0.y);
            afr[kk].u[2] = f2b(x0.z); afr[kk].u[3] = f2b(x0.w);
            afr[kk].u[4] = f2b(x1.x); afr[kk].u[5] = f2b(x1.y);
            afr[kk].u[6] = f2b(x1.z); afr[kk].u[7] = f2b(x1.w);
        }
    } else {
        const u16* xr = (const u16*)xv + ((size_t)(b * 2048 + i_a)) * 128;
#pragma unroll
        for (int kk = 0; kk < 4; ++kk) {
            const int o8 = kk * 32 + quad * 8;
            u16x8 xa = *reinterpret_cast<const u16x8*>(xr + o8);
            afr[kk].u = xa;
            float4 s0 = *reinterpret_cast<const float4*>(us + o8);
            float4 s1 = *reinterpret_cast<const float4*>(us + o8 + 4);
            float4 d0 = *reinterpret_cast<const float4*>(ud + o8);
            float4 d1 = *reinterpret_cast<const float4*>(ud + o8 + 4);
            float xf[8];
#pragma unroll
            for (int j = 0; j < 8; ++j) xf[j] = b2f(xa[j]);
            ps += xf[0] * s0.x + xf[1] * s0.y + xf[2] * s0.z + xf[3] * s0.w
                + xf[4] * s1.x + xf[5] * s1.y + xf[6] * s1.z + xf[7] * s1.w;
            pd += xf[0] * d0.x + xf[1] * d0.y + xf[2] * d0.z + xf[3] * d0.w
                + xf[4] * d1.x + xf[5] * d1.y + xf[6] * d1.z + xf[7] * d1.w;
        }
    }
    // reduce logit partials across the 4 quads sharing l15 (full 128-dot)
    ps += __shfl_xor(ps, 16, 64); ps += __shfl_xor(ps, 32, 64);
    pd += __shfl_xor(pd, 16, 64); pd += __shfl_xor(pd, 32, 64);
    if (quad == 0) {
        es2[b * 2048 + i_a] = ps;            // already *log2e via u pre-scale
        ed2[b * 2048 + i_a] = pd;
    }

    f32x4 acc[NT];
#pragma unroll
    for (int nt = 0; nt < NT; ++nt) acc[nt] = (f32x4){0.f, 0.f, 0.f, 0.f};
#pragma unroll
    for (int kk = 0; kk < 4; ++kk) {
#pragma unroll
        for (int nt = 0; nt < NT; ++nt) {
            bf16x8 bfv = *reinterpret_cast<const bf16x8*>(
                Wt + (nt * 16 + l15) * 128 + kk * 32 + quad * 8);
            acc[nt] = __builtin_amdgcn_mfma_f32_16x16x32_bf16(afr[kk].v, bfv, acc[nt], 0, 0, 0);
        }
    }

    // stage transposed tile to LDS (D: col=l15 -> o, row=quad*4+r -> i), then
    // coalesced global write of h^T[b][o][n]
#pragma unroll
    for (int nt = 0; nt < NT; ++nt)
#pragma unroll
        for (int r = 0; r < 4; ++r)
            hl[(nt * 16 + l15) * TNP + w * 16 + quad * 4 + r] = f2b(acc[nt][r]);
    __syncthreads();
    if (tid < F * 2) {
        int o = tid >> 1, half = tid & 1;
        const u16* src = hl + o * TNP + half * 32;
        u16* dst = h_t + ((size_t)(b * F + o)) * 2048 + nblk * 64 + half * 32;
#pragma unroll
        for (int c = 0; c < 4; ++c)
            *reinterpret_cast<u16x8*>(dst + c * 8) =
                *reinterpret_cast<const u16x8*>(src + c * 8);
    }
}

// ---------------- k_attn: fused masked-softmax(P) @ H, flash-style, MFMA.
// grid (8, 32) = (b, iblk), block 256 (4 waves x 16 i-rows), full j sweep.
template <int F, bool OUT_F32>
__global__ void __launch_bounds__(256) k_attn(const float* __restrict__ es2,
                                              const float* __restrict__ ed2,
                                              const float* __restrict__ adj,
                                              const u16* __restrict__ h_t,
                                              void* __restrict__ outp) {
    constexpr int NT = F / 16;
    __shared__ __align__(16) u16 Ht[F * 64];   // H^T tile [F][64 j], xor-swizzled 16B chunks

    const int b = blockIdx.x;
    const int iblk = blockIdx.y;
    const int tid = threadIdx.x;
    const int w = tid >> 6, lane = tid & 63;
    const int quad = lane >> 4, l15 = lane & 15;
    const int i_a = iblk * 64 + w * 16 + l15;

    const float esv = es2[b * 2048 + i_a];
    const float* edb = ed2 + b * 2048;
    const float* adjrow = adj + (size_t)i_a * 2048;
    const u16* hb = h_t + (size_t)b * F * 2048;

    f32x4 acc[NT];
#pragma unroll
    for (int nt = 0; nt < NT; ++nt) acc[nt] = (f32x4){0.f, 0.f, 0.f, 0.f};
    float dacc = 0.f;

    for (int jt = 0; jt < 32; ++jt) {
        const int j0 = jt * 64;
        // stage H^T tile (async). lds chunk c' of row o holds global chunk c'^(o&7)
#pragma unroll
        for (int it = 0; it < F / 32; ++it) {
            int ro = (it * 4 + w) * 8 + (lane >> 3);
            int cp = lane & 7;
            int c = cp ^ (ro & 7);
            gload_lds16(hb + (size_t)ro * 2048 + j0 + c * 8, Ht + (it * 4 + w) * 512);
        }
        // compute P fragments directly in A-operand layout (overlaps staging)
        ABfrag af[2];
#pragma unroll
        for (int kk = 0; kk < 2; ++kk) {
            int jb = j0 + kk * 32 + quad * 8;
            float4 e0 = *reinterpret_cast<const float4*>(edb + jb);
            float4 e1 = *reinterpret_cast<const float4*>(edb + jb + 4);
            float4 a0 = *reinterpret_cast<const float4*>(adjrow + jb);
            float4 a1 = *reinterpret_cast<const float4*>(adjrow + jb + 4);
            float ed[8] = {e0.x, e0.y, e0.z, e0.w, e1.x, e1.y, e1.z, e1.w};
            float ad[8] = {a0.x, a0.y, a0.z, a0.w, a1.x, a1.y, a1.z, a1.w};
#pragma unroll
            for (int jj = 0; jj < 8; ++jj) {
                float e = esv + ed[jj];               // already *log2e
                float v = fmaxf(e, 0.2f * e);         // leaky_relu (scale-commutes)
                float wv = exp2f(v);
                wv = (ad[jj] > 0.f) ? wv : 0.f;       // mask
                u16 wb = f2b(wv);
                af[kk].u[jj] = wb;
                dacc += b2f(wb);                      // denom consistent with rounded P
            }
        }
        __syncthreads();                              // staging drained (vmcnt) + visible
#pragma unroll
        for (int kk = 0; kk < 2; ++kk) {
#pragma unroll
            for (int nt = 0; nt < NT; ++nt) {
                int ob = nt * 16 + l15;
                int c = kk * 4 + quad;
                bf16x8 bfv = *reinterpret_cast<const bf16x8*>(
                    Ht + ob * 64 + ((c ^ (ob & 7)) * 8));
                acc[nt] = __builtin_amdgcn_mfma_f32_16x16x32_bf16(af[kk].v, bfv, acc[nt], 0, 0, 0);
            }
        }
        __syncthreads();                              // tile consumed before overwrite
    }

    // denom: reduce over quads; lane l15 then holds full sum for row w*16+l15
    dacc += __shfl_xor(dacc, 16, 64);
    dacc += __shfl_xor(dacc, 32, 64);
    float dinv[4];
#pragma unroll
    for (int r = 0; r < 4; ++r)
        dinv[r] = 1.0f / fmaxf(__shfl(dacc, quad * 4 + r, 64), 1e-30f);

    const int ib = iblk * 64 + w * 16 + quad * 4;
    if (OUT_F32) {
        float* o3 = (float*)outp;
#pragma unroll
        for (int nt = 0; nt < NT; ++nt)
#pragma unroll
            for (int r = 0; r < 4; ++r) {
                float vv = fmaxf(acc[nt][r] * dinv[r], 0.f);   // relu
                o3[((size_t)(b * 2048 + ib + r)) * F + nt * 16 + l15] = vv;
            }
    } else {
        u16* xo = (u16*)outp;
#pragma unroll
        for (int nt = 0; nt < NT; ++nt)
#pragma unroll
            for (int r = 0; r < 4; ++r) {
                float vv = fmaxf(acc[nt][r] * dinv[r], 0.f);
                xo[((size_t)(b * 2048 + ib + r)) * F + nt * 16 + l15] = f2b(vv);
            }
    }
}

// ---------------- final linear: [8,131072] fp32 @ [131072,128] fp32, split-K + atomics
__global__ void __launch_bounds__(256) k_lin(const float* __restrict__ o3,
                                             const float* __restrict__ Wlin,
                                             float* __restrict__ outf) {
    __shared__ float xc[8][512];
    const int tid = threadIdx.x;
    const int k0 = blockIdx.x * 512;
    for (int idx = tid; idx < 8 * 512; idx += 256) {
        int bb = idx >> 9, kk = idx & 511;
        xc[bb][kk] = o3[(size_t)bb * 131072 + k0 + kk];
    }
    __syncthreads();
    const int o2 = tid & 63;     // outputs 2*o2, 2*o2+1
    const int bq = tid >> 6;     // batches 2*bq, 2*bq+1
    float a00 = 0.f, a01 = 0.f, a10 = 0.f, a11 = 0.f;
#pragma unroll 8
    for (int kk = 0; kk < 512; ++kk) {
        float2 wv = *reinterpret_cast<const float2*>(Wlin + (size_t)(k0 + kk) * 128 + 2 * o2);
        float x0 = xc[2 * bq][kk], x1 = xc[2 * bq + 1][kk];
        a00 += x0 * wv.x; a01 += x0 * wv.y;
        a10 += x1 * wv.x; a11 += x1 * wv.y;
    }
    atomicAdd(&outf[(2 * bq) * 128 + 2 * o2], a00);
    atomicAdd(&outf[(2 * bq) * 128 + 2 * o2 + 1], a01);
    atomicAdd(&outf[(2 * bq + 1) * 128 + 2 * o2], a10);
    atomicAdd(&outf[(2 * bq + 1) * 128 + 2 * o2 + 1], a11);
}

__global__ void k_bias(const float* __restrict__ outf, const float* __restrict__ blin,
                       float* __restrict__ out) {
    int idx = blockIdx.x * 256 + threadIdx.x;
    if (idx < 1024) out[idx] = outf[idx] + blin[idx & 127];
}

extern "C" void kernel_launch(void* const* d_in, const int* in_sizes, int n_in,
                              void* d_out, int out_size, void* d_ws, size_t ws_size,
                              hipStream_t stream) {
    (void)in_sizes; (void)n_in; (void)out_size;
    const float* x    = (const float*)d_in[0];
    const float* adj  = (const float*)d_in[1];
    const float* W1   = (const float*)d_in[2];
    const float* a1s  = (const float*)d_in[3];
    const float* a1d  = (const float*)d_in[4];
    const float* W2   = (const float*)d_in[5];
    const float* a2s  = (const float*)d_in[6];
    const float* a2d  = (const float*)d_in[7];
    const float* W3   = (const float*)d_in[8];
    const float* a3s  = (const float*)d_in[9];
    const float* a3d  = (const float*)d_in[10];
    const float* Wlin = (const float*)d_in[11];
    const float* blin = (const float*)d_in[12];

    // ---- workspace layout (adaptive; never early-return) ----
    char* ws = (char*)d_ws;
    u16*   h_t = (u16*)ws;                          // 4 MB  [8][F][2048] bf16
    size_t off = (size_t)4 << 20;
    float* es2 = (float*)(ws + off); off += 65536;
    float* ed2 = (float*)(ws + off); off += 65536;
    u16*   Wt1 = (u16*)(ws + off);   off += 32768;
    u16*   Wt2 = (u16*)(ws + off);   off += 32768;
    u16*   Wt3 = (u16*)(ws + off);   off += 16384;
    float* u1s = (float*)(ws + off); off += 512;
    float* u1d = (float*)(ws + off); off += 512;
    float* u2s = (float*)(ws + off); off += 512;
    float* u2d = (float*)(ws + off); off += 512;
    float* u3s = (float*)(ws + off); off += 512;
    float* u3d = (float*)(ws + off); off += 512;
    float* outf = (float*)(ws + off); off += 4096;
    // activation ping (bf16 [8][2048][128] = 4MB) aliases layer-3 fp32 out
    // ([8][2048][64] fp32 = 4MB): disjoint live ranges. Fallback: alias the x
    // input (16MB fp32; dead after layer-1 k_h; restored by harness pre-launch).
    u16* actA;
    if (ws_size >= off + ((size_t)4 << 20)) {
        actA = (u16*)(ws + off);
    } else {
        actA = (u16*)d_in[0];
    }
    float* o3 = (float*)actA;

    dim3 g(8, 32);
    k_prep<<<161, 256, 0, stream>>>(W1, W2, W3, a1s, a1d, a2s, a2d, a3s, a3d,
                                    Wt1, Wt2, Wt3, u1s, u1d, u2s, u2d, u3s, u3d, outf);

    k_h<128, true ><<<g, 256, 0, stream>>>((const void*)x, Wt1, u1s, u1d, h_t, es2, ed2);
    k_attn<128, false><<<g, 256, 0, stream>>>(es2, ed2, adj, h_t, (void*)actA);

    k_h<128, false><<<g, 256, 0, stream>>>((const void*)actA, Wt2, u2s, u2d, h_t, es2, ed2);
    k_attn<128, false><<<g, 256, 0, stream>>>(es2, ed2, adj, h_t, (void*)actA);

    k_h<64, false><<<g, 256, 0, stream>>>((const void*)actA, Wt3, u3s, u3d, h_t, es2, ed2);
    k_attn<64, true ><<<g, 256, 0, stream>>>(es2, ed2, adj, h_t, (void*)o3);

    k_lin<<<256, 256, 0, stream>>>(o3, Wlin, outf);
    k_bias<<<4, 256, 0, stream>>>(outf, blin, (float*)d_out);
}

// Round 4
// 310.864 us; speedup vs baseline: 1.4192x; 1.4192x over previous
//
#include <hip/hip_runtime.h>
#include <stdint.h>

// GAT 3-layer + linear head, MI355X (gfx950).
// I/O is FP32 (per reference). Internals: bf16 MFMA for h and att@h
// (softmax-averaging damps bf16 rounding); logits and final linear in fp32.
// R4: adj -> packed bitmask (512KB, L2-resident); k_attn software-pipelined
// (double-buffered LDS H-tiles + register prefetch, one barrier/iter).

typedef unsigned short u16;
typedef __bf16 bf16x8 __attribute__((ext_vector_type(8)));
typedef float f32x4 __attribute__((ext_vector_type(4)));
typedef u16 u16x8 __attribute__((ext_vector_type(8)));

#define LOG2E 1.44269504088896340736f

__device__ __forceinline__ float b2f(u16 u) {
    union { unsigned int i; float f; } v; v.i = ((unsigned int)u) << 16; return v.f;
}
__device__ __forceinline__ u16 f2b(float f) {   // RNE round to bf16
    union { float f; unsigned int i; } v; v.f = f;
    unsigned int i = v.i;
    return (u16)((i + 0x7fffu + ((i >> 16) & 1u)) >> 16);
}
__device__ __forceinline__ float fast_exp2(float x) {
#if __has_builtin(__builtin_amdgcn_exp2f)
    return __builtin_amdgcn_exp2f(x);
#else
    return exp2f(x);
#endif
}

union ABfrag { bf16x8 v; u16x8 u; };

__device__ __forceinline__ void gload_lds16(const u16* g, u16* l) {
    // async global->LDS, 16B/lane, LDS dest = wave-uniform base + lane*16
    __builtin_amdgcn_global_load_lds((const __attribute__((address_space(1))) void*)g,
                                     (__attribute__((address_space(3))) void*)l,
                                     16, 0, 0);
}

// ---------------- k_mask: adjacency bitmask, adjm[row][64] uint32 (bit j of row)
__global__ void __launch_bounds__(256) k_mask(const float* __restrict__ adj,
                                              uint32_t* __restrict__ adjm) {
    const int w = threadIdx.x >> 6, lane = threadIdx.x & 63;
    const int row = blockIdx.x * 4 + w;
    const float* ar = adj + (size_t)row * 2048;
    uint32_t* mr = adjm + (size_t)row * 64;
    for (int j0 = 0; j0 < 2048; j0 += 64) {
        unsigned long long m = __ballot(ar[j0 + lane] > 0.f);
        if (lane == 0) {
            mr[(j0 >> 5)] = (uint32_t)m;
            mr[(j0 >> 5) + 1] = (uint32_t)(m >> 32);
        }
    }
}

// ---------------- prep: bf16-transpose W's, u = (W @ a)*log2e (fp32), zero outf
__global__ void k_prep(const float* __restrict__ W1, const float* __restrict__ W2,
                       const float* __restrict__ W3,
                       const float* __restrict__ a1s, const float* __restrict__ a1d,
                       const float* __restrict__ a2s, const float* __restrict__ a2d,
                       const float* __restrict__ a3s, const float* __restrict__ a3d,
                       u16* __restrict__ Wt1, u16* __restrict__ Wt2, u16* __restrict__ Wt3,
                       float* __restrict__ u1s, float* __restrict__ u1d,
                       float* __restrict__ u2s, float* __restrict__ u2d,
                       float* __restrict__ u3s, float* __restrict__ u3d,
                       float* __restrict__ outf) {
    if (blockIdx.x == 160) {                 // u-vectors: fp32 matvecs, trivial size
        int f = threadIdx.x;
        if (f < 128) {
            float s1 = 0.f, d1 = 0.f, s2 = 0.f, d2 = 0.f, s3 = 0.f, d3 = 0.f;
            for (int o = 0; o < 128; ++o) { float w = W1[f * 128 + o]; s1 += w * a1s[o]; d1 += w * a1d[o]; }
            for (int o = 0; o < 128; ++o) { float w = W2[f * 128 + o]; s2 += w * a2s[o]; d2 += w * a2d[o]; }
            for (int o = 0; o <  64; ++o) { float w = W3[f *  64 + o]; s3 += w * a3s[o]; d3 += w * a3d[o]; }
            u1s[f] = s1 * LOG2E; u1d[f] = d1 * LOG2E;
            u2s[f] = s2 * LOG2E; u2d[f] = d2 * LOG2E;
            u3s[f] = s3 * LOG2E; u3d[f] = d3 * LOG2E;
        }
        return;
    }
    int idx = blockIdx.x * 256 + threadIdx.x;
    if (idx < 1024) outf[idx] = 0.0f;
    if (idx < 16384) {                       // W1: [128,128] -> Wt1[o][f] bf16
        int f = idx >> 7, o = idx & 127;
        Wt1[o * 128 + f] = f2b(W1[idx]);
    } else if (idx < 32768) {                // W2
        int j = idx - 16384; int f = j >> 7, o = j & 127;
        Wt2[o * 128 + f] = f2b(W2[j]);
    } else if (idx < 40960) {                // W3: [128,64] -> Wt3[o][f]
        int j = idx - 32768; int f = j >> 6, o = j & 63;
        Wt3[o * 128 + f] = f2b(W3[j]);
    }
}

// ---------------- k_h: h = act @ W (bf16 MFMA) -> h^T bf16; es/ed = act . u (fp32)
// grid (8, 32) = (b, nblk), block 256 (4 waves x 16 rows). K = 128 always.
template <int F, bool XF32>
__global__ void __launch_bounds__(256) k_h(const void* __restrict__ xv,
                                           const u16* __restrict__ Wt,
                                           const float* __restrict__ us,
                                           const float* __restrict__ ud,
                                           u16* __restrict__ h_t,
                                           float* __restrict__ es2,
                                           float* __restrict__ ed2) {
    constexpr int NT = F / 16;
    constexpr int TNP = 72;                  // padded n-stride (144B = 9x16B)
    __shared__ __align__(16) u16 hl[F * TNP];

    const int b = blockIdx.x;
    const int nblk = blockIdx.y;
    const int tid = threadIdx.x;
    const int w = tid >> 6, lane = tid & 63;
    const int quad = lane >> 4, l15 = lane & 15;
    const int n0w = nblk * 64 + w * 16;
    const int i_a = n0w + l15;               // A-operand row (m = lane&15)

    ABfrag afr[4];
    float ps = 0.f, pd = 0.f;
    if (XF32) {
        const float* xr = (const float*)xv + ((size_t)(b * 2048 + i_a)) * 128;
#pragma unroll
        for (int kk = 0; kk < 4; ++kk) {
            const int o8 = kk * 32 + quad * 8;
            float4 x0 = *reinterpret_cast<const float4*>(xr + o8);
            float4 x1 = *reinterpret_cast<const float4*>(xr + o8 + 4);
            float4 s0 = *reinterpret_cast<const float4*>(us + o8);
            float4 s1 = *reinterpret_cast<const float4*>(us + o8 + 4);
            float4 d0 = *reinterpret_cast<const float4*>(ud + o8);
            float4 d1 = *reinterpret_cast<const float4*>(ud + o8 + 4);
            ps += x0.x * s0.x + x0.y * s0.y + x0.z * s0.z + x0.w * s0.w
                + x1.x * s1.x + x1.y * s1.y + x1.z * s1.z + x1.w * s1.w;
            pd += x0.x * d0.x + x0.y * d0.y + x0.z * d0.z + x0.w * d0.w
                + x1.x * d1.x + x1.y * d1.y + x1.z * d1.z + x1.w * d1.w;
            afr[kk].u[0] = f2b(x0.x); afr[kk].u[1] = f2b(x0.y);
            afr[kk].u[2] = f2b(x0.z); afr[kk].u[3] = f2b(x0.w);
            afr[kk].u[4] = f2b(x1.x); afr[kk].u[5] = f2b(x1.y);
            afr[kk].u[6] = f2b(x1.z); afr[kk].u[7] = f2b(x1.w);
        }
    } else {
        const u16* xr = (const u16*)xv + ((size_t)(b * 2048 + i_a)) * 128;
#pragma unroll
        for (int kk = 0; kk < 4; ++kk) {
            const int o8 = kk * 32 + quad * 8;
            u16x8 xa = *reinterpret_cast<const u16x8*>(xr + o8);
            afr[kk].u = xa;
            float4 s0 = *reinterpret_cast<const float4*>(us + o8);
            float4 s1 = *reinterpret_cast<const float4*>(us + o8 + 4);
            float4 d0 = *reinterpret_cast<const float4*>(ud + o8);
            float4 d1 = *reinterpret_cast<const float4*>(ud + o8 + 4);
            float xf[8];
#pragma unroll
            for (int j = 0; j < 8; ++j) xf[j] = b2f(xa[j]);
            ps += xf[0] * s0.x + xf[1] * s0.y + xf[2] * s0.z + xf[3] * s0.w
                + xf[4] * s1.x + xf[5] * s1.y + xf[6] * s1.z + xf[7] * s1.w;
            pd += xf[0] * d0.x + xf[1] * d0.y + xf[2] * d0.z + xf[3] * d0.w
                + xf[4] * d1.x + xf[5] * d1.y + xf[6] * d1.z + xf[7] * d1.w;
        }
    }
    // reduce logit partials across the 4 quads sharing l15 (full 128-dot)
    ps += __shfl_xor(ps, 16, 64); ps += __shfl_xor(ps, 32, 64);
    pd += __shfl_xor(pd, 16, 64); pd += __shfl_xor(pd, 32, 64);
    if (quad == 0) {
        es2[b * 2048 + i_a] = ps;            // already *log2e via u pre-scale
        ed2[b * 2048 + i_a] = pd;
    }

    f32x4 acc[NT];
#pragma unroll
    for (int nt = 0; nt < NT; ++nt) acc[nt] = (f32x4){0.f, 0.f, 0.f, 0.f};
#pragma unroll
    for (int kk = 0; kk < 4; ++kk) {
#pragma unroll
        for (int nt = 0; nt < NT; ++nt) {
            bf16x8 bfv = *reinterpret_cast<const bf16x8*>(
                Wt + (nt * 16 + l15) * 128 + kk * 32 + quad * 8);
            acc[nt] = __builtin_amdgcn_mfma_f32_16x16x32_bf16(afr[kk].v, bfv, acc[nt], 0, 0, 0);
        }
    }

    // stage transposed tile to LDS (D: col=l15 -> o, row=quad*4+r -> i), then
    // coalesced global write of h^T[b][o][n]
#pragma unroll
    for (int nt = 0; nt < NT; ++nt)
#pragma unroll
        for (int r = 0; r < 4; ++r)
            hl[(nt * 16 + l15) * TNP + w * 16 + quad * 4 + r] = f2b(acc[nt][r]);
    __syncthreads();
    if (tid < F * 2) {
        int o = tid >> 1, half = tid & 1;
        const u16* src = hl + o * TNP + half * 32;
        u16* dst = h_t + ((size_t)(b * F + o)) * 2048 + nblk * 64 + half * 32;
#pragma unroll
        for (int c = 0; c < 4; ++c)
            *reinterpret_cast<u16x8*>(dst + c * 8) =
                *reinterpret_cast<const u16x8*>(src + c * 8);
    }
}

// ---------------- k_attn: fused masked-softmax(P) @ H, software-pipelined MFMA.
// grid (8, 32) = (b, iblk), block 256 (4 waves x 16 i-rows), full j sweep.
template <int F, bool OUT_F32>
__global__ void __launch_bounds__(256) k_attn(const float* __restrict__ es2,
                                              const float* __restrict__ ed2,
                                              const uint32_t* __restrict__ adjm,
                                              const u16* __restrict__ h_t,
                                              void* __restrict__ outp) {
    constexpr int NT = F / 16;
    __shared__ __align__(16) u16 Ht[2][F * 64];  // double-buffered H^T tiles, xor-swizzled

    const int b = blockIdx.x;
    const int iblk = blockIdx.y;
    const int tid = threadIdx.x;
    const int w = tid >> 6, lane = tid & 63;
    const int quad = lane >> 4, l15 = lane & 15;
    const int i_a = iblk * 64 + w * 16 + l15;

    const float esv = es2[b * 2048 + i_a];
    const float* edb = ed2 + b * 2048;
    const uint2* mrow = (const uint2*)(adjm + (size_t)i_a * 64);
    const u16* hb = h_t + (size_t)b * F * 2048;

    // lane ro/c for staging (constant across iters)
    const int lro = lane >> 3;
    const int lcp = lane & 7;

    f32x4 acc[NT];
#pragma unroll
    for (int nt = 0; nt < NT; ++nt) acc[nt] = (f32x4){0.f, 0.f, 0.f, 0.f};
    float dacc = 0.f;

    // ---- prologue: stage tile 0 + prefetch tile-0 regs
    {
        const int j0 = 0;
#pragma unroll
        for (int it = 0; it < F / 32; ++it) {
            int ro = (it * 4 + w) * 8 + lro;
            int c = lcp ^ (ro & 7);
            gload_lds16(hb + (size_t)ro * 2048 + j0 + c * 8, &Ht[0][(it * 4 + w) * 512]);
        }
    }
    float4 ec0 = *reinterpret_cast<const float4*>(edb + quad * 8);
    float4 ec1 = *reinterpret_cast<const float4*>(edb + quad * 8 + 4);
    float4 ec2 = *reinterpret_cast<const float4*>(edb + quad * 8 + 32);
    float4 ec3 = *reinterpret_cast<const float4*>(edb + quad * 8 + 36);
    uint2 mc = mrow[0];
    __syncthreads();                              // tile 0 staged (vmcnt drained)

    for (int jt = 0; jt < 32; ++jt) {
        const int cur = jt & 1, nxt = cur ^ 1;
        float4 en0, en1, en2, en3; uint2 mn;
        if (jt < 31) {
            const int j1 = (jt + 1) * 64;
#pragma unroll
            for (int it = 0; it < F / 32; ++it) {
                int ro = (it * 4 + w) * 8 + lro;
                int c = lcp ^ (ro & 7);
                gload_lds16(hb + (size_t)ro * 2048 + j1 + c * 8, &Ht[nxt][(it * 4 + w) * 512]);
            }
            en0 = *reinterpret_cast<const float4*>(edb + j1 + quad * 8);
            en1 = *reinterpret_cast<const float4*>(edb + j1 + quad * 8 + 4);
            en2 = *reinterpret_cast<const float4*>(edb + j1 + quad * 8 + 32);
            en3 = *reinterpret_cast<const float4*>(edb + j1 + quad * 8 + 36);
            mn = mrow[jt + 1];
        }

        // P fragments in A-operand layout from current regs
        ABfrag af[2];
        {
            float ed[16] = {ec0.x, ec0.y, ec0.z, ec0.w, ec1.x, ec1.y, ec1.z, ec1.w,
                            ec2.x, ec2.y, ec2.z, ec2.w, ec3.x, ec3.y, ec3.z, ec3.w};
#pragma unroll
            for (int kk = 0; kk < 2; ++kk) {
                uint32_t word = kk ? mc.y : mc.x;
#pragma unroll
                for (int jj = 0; jj < 8; ++jj) {
                    float e = esv + ed[kk * 8 + jj];      // already *log2e
                    float v = fmaxf(e, 0.2f * e);         // leaky_relu (scale-commutes)
                    float wv = fast_exp2(v);
                    bool bit = (word >> (quad * 8 + jj)) & 1u;
                    wv = bit ? wv : 0.f;
                    u16 wb = f2b(wv);
                    af[kk].u[jj] = wb;
                    dacc += b2f(wb);                      // denom consistent with rounded P
                }
            }
        }

        // MFMA over current LDS tile
#pragma unroll
        for (int kk = 0; kk < 2; ++kk) {
#pragma unroll
            for (int nt = 0; nt < NT; ++nt) {
                int ob = nt * 16 + l15;
                int c = kk * 4 + quad;
                bf16x8 bfv = *reinterpret_cast<const bf16x8*>(
                    &Ht[cur][ob * 64 + ((c ^ (ob & 7)) * 8)]);
                acc[nt] = __builtin_amdgcn_mfma_f32_16x16x32_bf16(af[kk].v, bfv, acc[nt], 0, 0, 0);
            }
        }

        if (jt < 31) { ec0 = en0; ec1 = en1; ec2 = en2; ec3 = en3; mc = mn; }
        __syncthreads();   // drains next-tile staging; cur fully consumed before overwrite
    }

    // denom: reduce over quads; lane l15 then holds full sum for row w*16+l15
    dacc += __shfl_xor(dacc, 16, 64);
    dacc += __shfl_xor(dacc, 32, 64);
    float dinv[4];
#pragma unroll
    for (int r = 0; r < 4; ++r)
        dinv[r] = 1.0f / fmaxf(__shfl(dacc, quad * 4 + r, 64), 1e-30f);

    const int ib = iblk * 64 + w * 16 + quad * 4;
    if (OUT_F32) {
        float* o3 = (float*)outp;
#pragma unroll
        for (int nt = 0; nt < NT; ++nt)
#pragma unroll
            for (int r = 0; r < 4; ++r) {
                float vv = fmaxf(acc[nt][r] * dinv[r], 0.f);   // relu
                o3[((size_t)(b * 2048 + ib + r)) * F + nt * 16 + l15] = vv;
            }
    } else {
        u16* xo = (u16*)outp;
#pragma unroll
        for (int nt = 0; nt < NT; ++nt)
#pragma unroll
            for (int r = 0; r < 4; ++r) {
                float vv = fmaxf(acc[nt][r] * dinv[r], 0.f);
                xo[((size_t)(b * 2048 + ib + r)) * F + nt * 16 + l15] = f2b(vv);
            }
    }
}

// ---------------- final linear: [8,131072] fp32 @ [131072,128] fp32, split-K + atomics
__global__ void __launch_bounds__(256) k_lin(const float* __restrict__ o3,
                                             const float* __restrict__ Wlin,
                                             float* __restrict__ outf) {
    __shared__ float xc[8][512];
    const int tid = threadIdx.x;
    const int k0 = blockIdx.x * 512;
    for (int idx = tid; idx < 8 * 512; idx += 256) {
        int bb = idx >> 9, kk = idx & 511;
        xc[bb][kk] = o3[(size_t)bb * 131072 + k0 + kk];
    }
    __syncthreads();
    const int o2 = tid & 63;     // outputs 2*o2, 2*o2+1
    const int bq = tid >> 6;     // batches 2*bq, 2*bq+1
    float a00 = 0.f, a01 = 0.f, a10 = 0.f, a11 = 0.f;
#pragma unroll 8
    for (int kk = 0; kk < 512; ++kk) {
        float2 wv = *reinterpret_cast<const float2*>(Wlin + (size_t)(k0 + kk) * 128 + 2 * o2);
        float x0 = xc[2 * bq][kk], x1 = xc[2 * bq + 1][kk];
        a00 += x0 * wv.x; a01 += x0 * wv.y;
        a10 += x1 * wv.x; a11 += x1 * wv.y;
    }
    atomicAdd(&outf[(2 * bq) * 128 + 2 * o2], a00);
    atomicAdd(&outf[(2 * bq) * 128 + 2 * o2 + 1], a01);
    atomicAdd(&outf[(2 * bq + 1) * 128 + 2 * o2], a10);
    atomicAdd(&outf[(2 * bq + 1) * 128 + 2 * o2 + 1], a11);
}

__global__ void k_bias(const float* __restrict__ outf, const float* __restrict__ blin,
                       float* __restrict__ out) {
    int idx = blockIdx.x * 256 + threadIdx.x;
    if (idx < 1024) out[idx] = outf[idx] + blin[idx & 127];
}

extern "C" void kernel_launch(void* const* d_in, const int* in_sizes, int n_in,
                              void* d_out, int out_size, void* d_ws, size_t ws_size,
                              hipStream_t stream) {
    (void)in_sizes; (void)n_in; (void)out_size;
    const float* x    = (const float*)d_in[0];
    const float* adj  = (const float*)d_in[1];
    const float* W1   = (const float*)d_in[2];
    const float* a1s  = (const float*)d_in[3];
    const float* a1d  = (const float*)d_in[4];
    const float* W2   = (const float*)d_in[5];
    const float* a2s  = (const float*)d_in[6];
    const float* a2d  = (const float*)d_in[7];
    const float* W3   = (const float*)d_in[8];
    const float* a3s  = (const float*)d_in[9];
    const float* a3d  = (const float*)d_in[10];
    const float* Wlin = (const float*)d_in[11];
    const float* blin = (const float*)d_in[12];

    // ---- workspace layout (adaptive; never early-return) ----
    char* ws = (char*)d_ws;
    u16*   h_t = (u16*)ws;                          // 4 MB  [8][F][2048] bf16
    size_t off = (size_t)4 << 20;
    float* es2 = (float*)(ws + off); off += 65536;
    float* ed2 = (float*)(ws + off); off += 65536;
    u16*   Wt1 = (u16*)(ws + off);   off += 32768;
    u16*   Wt2 = (u16*)(ws + off);   off += 32768;
    u16*   Wt3 = (u16*)(ws + off);   off += 16384;
    float* u1s = (float*)(ws + off); off += 512;
    float* u1d = (float*)(ws + off); off += 512;
    float* u2s = (float*)(ws + off); off += 512;
    float* u2d = (float*)(ws + off); off += 512;
    float* u3s = (float*)(ws + off); off += 512;
    float* u3d = (float*)(ws + off); off += 512;
    float* outf = (float*)(ws + off); off += 4096;
    uint32_t* adjm = (uint32_t*)(ws + off); off += 524288;   // [2048][64] bitmask
    // activation ping (bf16 [8][2048][128] = 4MB) aliases layer-3 fp32 out
    // ([8][2048][64] fp32 = 4MB): disjoint live ranges. Fallback: alias the x
    // input (16MB fp32; dead after layer-1 k_h; restored by harness pre-launch).
    u16* actA;
    if (ws_size >= off + ((size_t)4 << 20)) {
        actA = (u16*)(ws + off);
    } else {
        actA = (u16*)d_in[0];
    }
    float* o3 = (float*)actA;

    dim3 g(8, 32);
    k_mask<<<512, 256, 0, stream>>>(adj, adjm);
    k_prep<<<161, 256, 0, stream>>>(W1, W2, W3, a1s, a1d, a2s, a2d, a3s, a3d,
                                    Wt1, Wt2, Wt3, u1s, u1d, u2s, u2d, u3s, u3d, outf);

    k_h<128, true ><<<g, 256, 0, stream>>>((const void*)x, Wt1, u1s, u1d, h_t, es2, ed2);
    k_attn<128, false><<<g, 256, 0, stream>>>(es2, ed2, adjm, h_t, (void*)actA);

    k_h<128, false><<<g, 256, 0, stream>>>((const void*)actA, Wt2, u2s, u2d, h_t, es2, ed2);
    k_attn<128, false><<<g, 256, 0, stream>>>(es2, ed2, adjm, h_t, (void*)actA);

    k_h<64, false><<<g, 256, 0, stream>>>((const void*)actA, Wt3, u3s, u3d, h_t, es2, ed2);
    k_attn<64, true ><<<g, 256, 0, stream>>>(es2, ed2, adjm, h_t, (void*)o3);

    k_lin<<<256, 256, 0, stream>>>(o3, Wlin, outf);
    k_bias<<<4, 256, 0, stream>>>(outf, blin, (float*)d_out);
}

// Round 5
// 292.899 us; speedup vs baseline: 1.5063x; 1.0613x over previous
//
#include <hip/hip_runtime.h>
#include <stdint.h>

// GAT 3-layer + linear head, MI355X (gfx950).
// I/O is FP32 (per reference). Internals: bf16 MFMA for h and att@h
// (softmax-averaging damps bf16 rounding); logits and final linear in fp32.
// R5: k_lin rewritten as high-MLP streaming split-K (partials, no atomics);
// k_attn 512-thread blocks with 2 independent j-groups (2 waves/SIMD).

typedef unsigned short u16;
typedef __bf16 bf16x8 __attribute__((ext_vector_type(8)));
typedef float f32x4 __attribute__((ext_vector_type(4)));
typedef u16 u16x8 __attribute__((ext_vector_type(8)));

#define LOG2E 1.44269504088896340736f

__device__ __forceinline__ float b2f(u16 u) {
    union { unsigned int i; float f; } v; v.i = ((unsigned int)u) << 16; return v.f;
}
__device__ __forceinline__ u16 f2b(float f) {   // RNE round to bf16
    union { float f; unsigned int i; } v; v.f = f;
    unsigned int i = v.i;
    return (u16)((i + 0x7fffu + ((i >> 16) & 1u)) >> 16);
}
__device__ __forceinline__ float fast_exp2(float x) {
#if __has_builtin(__builtin_amdgcn_exp2f)
    return __builtin_amdgcn_exp2f(x);
#else
    return exp2f(x);
#endif
}

union ABfrag { bf16x8 v; u16x8 u; };

__device__ __forceinline__ void gload_lds16(const u16* g, u16* l) {
    // async global->LDS, 16B/lane, LDS dest = wave-uniform base + lane*16
    __builtin_amdgcn_global_load_lds((const __attribute__((address_space(1))) void*)g,
                                     (__attribute__((address_space(3))) void*)l,
                                     16, 0, 0);
}

// ---------------- k_mask: adjacency bitmask, adjm[row][64] uint32 (bit j of row)
__global__ void __launch_bounds__(256) k_mask(const float* __restrict__ adj,
                                              uint32_t* __restrict__ adjm) {
    const int w = threadIdx.x >> 6, lane = threadIdx.x & 63;
    const int row = blockIdx.x * 4 + w;
    const float* ar = adj + (size_t)row * 2048;
    uint32_t* mr = adjm + (size_t)row * 64;
    for (int j0 = 0; j0 < 2048; j0 += 64) {
        unsigned long long m = __ballot(ar[j0 + lane] > 0.f);
        if (lane == 0) {
            mr[(j0 >> 5)] = (uint32_t)m;
            mr[(j0 >> 5) + 1] = (uint32_t)(m >> 32);
        }
    }
}

// ---------------- prep: bf16-transpose W's, u = (W @ a)*log2e (fp32)
__global__ void k_prep(const float* __restrict__ W1, const float* __restrict__ W2,
                       const float* __restrict__ W3,
                       const float* __restrict__ a1s, const float* __restrict__ a1d,
                       const float* __restrict__ a2s, const float* __restrict__ a2d,
                       const float* __restrict__ a3s, const float* __restrict__ a3d,
                       u16* __restrict__ Wt1, u16* __restrict__ Wt2, u16* __restrict__ Wt3,
                       float* __restrict__ u1s, float* __restrict__ u1d,
                       float* __restrict__ u2s, float* __restrict__ u2d,
                       float* __restrict__ u3s, float* __restrict__ u3d) {
    if (blockIdx.x == 160) {                 // u-vectors: fp32 matvecs, trivial size
        int f = threadIdx.x;
        if (f < 128) {
            float s1 = 0.f, d1 = 0.f, s2 = 0.f, d2 = 0.f, s3 = 0.f, d3 = 0.f;
            for (int o = 0; o < 128; ++o) { float w = W1[f * 128 + o]; s1 += w * a1s[o]; d1 += w * a1d[o]; }
            for (int o = 0; o < 128; ++o) { float w = W2[f * 128 + o]; s2 += w * a2s[o]; d2 += w * a2d[o]; }
            for (int o = 0; o <  64; ++o) { float w = W3[f *  64 + o]; s3 += w * a3s[o]; d3 += w * a3d[o]; }
            u1s[f] = s1 * LOG2E; u1d[f] = d1 * LOG2E;
            u2s[f] = s2 * LOG2E; u2d[f] = d2 * LOG2E;
            u3s[f] = s3 * LOG2E; u3d[f] = d3 * LOG2E;
        }
        return;
    }
    int idx = blockIdx.x * 256 + threadIdx.x;
    if (idx < 16384) {                       // W1: [128,128] -> Wt1[o][f] bf16
        int f = idx >> 7, o = idx & 127;
        Wt1[o * 128 + f] = f2b(W1[idx]);
    } else if (idx < 32768) {                // W2
        int j = idx - 16384; int f = j >> 7, o = j & 127;
        Wt2[o * 128 + f] = f2b(W2[j]);
    } else if (idx < 40960) {                // W3: [128,64] -> Wt3[o][f]
        int j = idx - 32768; int f = j >> 6, o = j & 63;
        Wt3[o * 128 + f] = f2b(W3[j]);
    }
}

// ---------------- k_h: h = act @ W (bf16 MFMA) -> h^T bf16; es/ed = act . u (fp32)
// grid (8, 32) = (b, nblk), block 256 (4 waves x 16 rows). K = 128 always.
template <int F, bool XF32>
__global__ void __launch_bounds__(256) k_h(const void* __restrict__ xv,
                                           const u16* __restrict__ Wt,
                                           const float* __restrict__ us,
                                           const float* __restrict__ ud,
                                           u16* __restrict__ h_t,
                                           float* __restrict__ es2,
                                           float* __restrict__ ed2) {
    constexpr int NT = F / 16;
    constexpr int TNP = 72;                  // padded n-stride (144B = 9x16B)
    __shared__ __align__(16) u16 hl[F * TNP];

    const int b = blockIdx.x;
    const int nblk = blockIdx.y;
    const int tid = threadIdx.x;
    const int w = tid >> 6, lane = tid & 63;
    const int quad = lane >> 4, l15 = lane & 15;
    const int n0w = nblk * 64 + w * 16;
    const int i_a = n0w + l15;               // A-operand row (m = lane&15)

    ABfrag afr[4];
    float ps = 0.f, pd = 0.f;
    if (XF32) {
        const float* xr = (const float*)xv + ((size_t)(b * 2048 + i_a)) * 128;
#pragma unroll
        for (int kk = 0; kk < 4; ++kk) {
            const int o8 = kk * 32 + quad * 8;
            float4 x0 = *reinterpret_cast<const float4*>(xr + o8);
            float4 x1 = *reinterpret_cast<const float4*>(xr + o8 + 4);
            float4 s0 = *reinterpret_cast<const float4*>(us + o8);
            float4 s1 = *reinterpret_cast<const float4*>(us + o8 + 4);
            float4 d0 = *reinterpret_cast<const float4*>(ud + o8);
            float4 d1 = *reinterpret_cast<const float4*>(ud + o8 + 4);
            ps += x0.x * s0.x + x0.y * s0.y + x0.z * s0.z + x0.w * s0.w
                + x1.x * s1.x + x1.y * s1.y + x1.z * s1.z + x1.w * s1.w;
            pd += x0.x * d0.x + x0.y * d0.y + x0.z * d0.z + x0.w * d0.w
                + x1.x * d1.x + x1.y * d1.y + x1.z * d1.z + x1.w * d1.w;
            afr[kk].u[0] = f2b(x0.x); afr[kk].u[1] = f2b(x0.y);
            afr[kk].u[2] = f2b(x0.z); afr[kk].u[3] = f2b(x0.w);
            afr[kk].u[4] = f2b(x1.x); afr[kk].u[5] = f2b(x1.y);
            afr[kk].u[6] = f2b(x1.z); afr[kk].u[7] = f2b(x1.w);
        }
    } else {
        const u16* xr = (const u16*)xv + ((size_t)(b * 2048 + i_a)) * 128;
#pragma unroll
        for (int kk = 0; kk < 4; ++kk) {
            const int o8 = kk * 32 + quad * 8;
            u16x8 xa = *reinterpret_cast<const u16x8*>(xr + o8);
            afr[kk].u = xa;
            float4 s0 = *reinterpret_cast<const float4*>(us + o8);
            float4 s1 = *reinterpret_cast<const float4*>(us + o8 + 4);
            float4 d0 = *reinterpret_cast<const float4*>(ud + o8);
            float4 d1 = *reinterpret_cast<const float4*>(ud + o8 + 4);
            float xf[8];
#pragma unroll
            for (int j = 0; j < 8; ++j) xf[j] = b2f(xa[j]);
            ps += xf[0] * s0.x + xf[1] * s0.y + xf[2] * s0.z + xf[3] * s0.w
                + xf[4] * s1.x + xf[5] * s1.y + xf[6] * s1.z + xf[7] * s1.w;
            pd += xf[0] * d0.x + xf[1] * d0.y + xf[2] * d0.z + xf[3] * d0.w
                + xf[4] * d1.x + xf[5] * d1.y + xf[6] * d1.z + xf[7] * d1.w;
        }
    }
    // reduce logit partials across the 4 quads sharing l15 (full 128-dot)
    ps += __shfl_xor(ps, 16, 64); ps += __shfl_xor(ps, 32, 64);
    pd += __shfl_xor(pd, 16, 64); pd += __shfl_xor(pd, 32, 64);
    if (quad == 0) {
        es2[b * 2048 + i_a] = ps;            // already *log2e via u pre-scale
        ed2[b * 2048 + i_a] = pd;
    }

    f32x4 acc[NT];
#pragma unroll
    for (int nt = 0; nt < NT; ++nt) acc[nt] = (f32x4){0.f, 0.f, 0.f, 0.f};
#pragma unroll
    for (int kk = 0; kk < 4; ++kk) {
#pragma unroll
        for (int nt = 0; nt < NT; ++nt) {
            bf16x8 bfv = *reinterpret_cast<const bf16x8*>(
                Wt + (nt * 16 + l15) * 128 + kk * 32 + quad * 8);
            acc[nt] = __builtin_amdgcn_mfma_f32_16x16x32_bf16(afr[kk].v, bfv, acc[nt], 0, 0, 0);
        }
    }

    // stage transposed tile to LDS (D: col=l15 -> o, row=quad*4+r -> i), then
    // coalesced global write of h^T[b][o][n]
#pragma unroll
    for (int nt = 0; nt < NT; ++nt)
#pragma unroll
        for (int r = 0; r < 4; ++r)
            hl[(nt * 16 + l15) * TNP + w * 16 + quad * 4 + r] = f2b(acc[nt][r]);
    __syncthreads();
    if (tid < F * 2) {
        int o = tid >> 1, half = tid & 1;
        const u16* src = hl + o * TNP + half * 32;
        u16* dst = h_t + ((size_t)(b * F + o)) * 2048 + nblk * 64 + half * 32;
#pragma unroll
        for (int c = 0; c < 4; ++c)
            *reinterpret_cast<u16x8*>(dst + c * 8) =
                *reinterpret_cast<const u16x8*>(src + c * 8);
    }
}

// ---------------- k_attn: fused masked-softmax(P) @ H, software-pipelined MFMA.
// grid (8, 32) = (b, iblk), block 512 = 2 j-groups x 4 waves x 16 i-rows.
// Each group sweeps half the j range with its own double-buffered LDS tiles;
// partial acc + denom combined through LDS at the end.
template <int F, bool OUT_F32>
__global__ void __launch_bounds__(512) k_attn(const float* __restrict__ es2,
                                              const float* __restrict__ ed2,
                                              const uint32_t* __restrict__ adjm,
                                              const u16* __restrict__ h_t,
                                              void* __restrict__ outp) {
    constexpr int NT = F / 16;
    __shared__ __align__(16) u16 Ht[2][2][F * 64];  // [grp][buf], xor-swizzled chunks
    __shared__ float dLDS[2][64];
    float* accLDS = (float*)&Ht[0][0][0];           // combine area (aliases tiles, used after)

    const int b = blockIdx.x;
    const int iblk = blockIdx.y;
    const int tid = threadIdx.x;
    const int grp = tid >> 8;                 // j-group 0/1
    const int t8 = tid & 255;
    const int w = t8 >> 6;                    // wave-within-group
    const int lane = tid & 63;
    const int quad = lane >> 4, l15 = lane & 15;
    const int i_a = iblk * 64 + w * 16 + l15;

    const float esv = es2[b * 2048 + i_a];
    const float* edb = ed2 + b * 2048;
    const uint2* mrow = (const uint2*)(adjm + (size_t)i_a * 64);
    const u16* hb = h_t + (size_t)b * F * 2048;

    const int lro = lane >> 3;
    const int lcp = lane & 7;
    const int jt0 = grp * 16;                 // this group's jt range [jt0, jt0+16)

    f32x4 acc[NT];
#pragma unroll
    for (int nt = 0; nt < NT; ++nt) acc[nt] = (f32x4){0.f, 0.f, 0.f, 0.f};
    float dacc = 0.f;

    // ---- prologue: stage this group's tile 0 + prefetch regs
    {
        const int j0 = jt0 * 64;
#pragma unroll
        for (int it = 0; it < F / 32; ++it) {
            int ro = (it * 4 + w) * 8 + lro;
            int c = lcp ^ (ro & 7);
            gload_lds16(hb + (size_t)ro * 2048 + j0 + c * 8, &Ht[grp][0][(it * 4 + w) * 512]);
        }
    }
    float4 ec0 = *reinterpret_cast<const float4*>(edb + jt0 * 64 + quad * 8);
    float4 ec1 = *reinterpret_cast<const float4*>(edb + jt0 * 64 + quad * 8 + 4);
    float4 ec2 = *reinterpret_cast<const float4*>(edb + jt0 * 64 + quad * 8 + 32);
    float4 ec3 = *reinterpret_cast<const float4*>(edb + jt0 * 64 + quad * 8 + 36);
    uint2 mc = mrow[jt0];
    __syncthreads();                          // both groups' tile 0 staged

    for (int jj = 0; jj < 16; ++jj) {
        const int cur = jj & 1, nxt = cur ^ 1;
        float4 en0, en1, en2, en3; uint2 mn;
        if (jj < 15) {
            const int j1 = (jt0 + jj + 1) * 64;
#pragma unroll
            for (int it = 0; it < F / 32; ++it) {
                int ro = (it * 4 + w) * 8 + lro;
                int c = lcp ^ (ro & 7);
                gload_lds16(hb + (size_t)ro * 2048 + j1 + c * 8, &Ht[grp][nxt][(it * 4 + w) * 512]);
            }
            en0 = *reinterpret_cast<const float4*>(edb + j1 + quad * 8);
            en1 = *reinterpret_cast<const float4*>(edb + j1 + quad * 8 + 4);
            en2 = *reinterpret_cast<const float4*>(edb + j1 + quad * 8 + 32);
            en3 = *reinterpret_cast<const float4*>(edb + j1 + quad * 8 + 36);
            mn = mrow[jt0 + jj + 1];
        }

        // P fragments in A-operand layout from current regs
        ABfrag af[2];
        {
            float ed[16] = {ec0.x, ec0.y, ec0.z, ec0.w, ec1.x, ec1.y, ec1.z, ec1.w,
                            ec2.x, ec2.y, ec2.z, ec2.w, ec3.x, ec3.y, ec3.z, ec3.w};
#pragma unroll
            for (int kk = 0; kk < 2; ++kk) {
                uint32_t word = kk ? mc.y : mc.x;
#pragma unroll
                for (int jx = 0; jx < 8; ++jx) {
                    float e = esv + ed[kk * 8 + jx];      // already *log2e
                    float v = fmaxf(e, 0.2f * e);         // leaky_relu (scale-commutes)
                    float wv = fast_exp2(v);
                    bool bit = (word >> (quad * 8 + jx)) & 1u;
                    wv = bit ? wv : 0.f;
                    u16 wb = f2b(wv);
                    af[kk].u[jx] = wb;
                    dacc += b2f(wb);                      // denom consistent with rounded P
                }
            }
        }

        // MFMA over current LDS tile
#pragma unroll
        for (int kk = 0; kk < 2; ++kk) {
#pragma unroll
            for (int nt = 0; nt < NT; ++nt) {
                int ob = nt * 16 + l15;
                int c = kk * 4 + quad;
                bf16x8 bfv = *reinterpret_cast<const bf16x8*>(
                    &Ht[grp][cur][ob * 64 + ((c ^ (ob & 7)) * 8)]);
                acc[nt] = __builtin_amdgcn_mfma_f32_16x16x32_bf16(af[kk].v, bfv, acc[nt], 0, 0, 0);
            }
        }

        if (jj < 15) { ec0 = en0; ec1 = en1; ec2 = en2; ec3 = en3; mc = mn; }
        __syncthreads();   // drains next-tile staging; cur consumed before overwrite
    }

    // group-partial denom: reduce over quads -> every lane holds its row's partial
    dacc += __shfl_xor(dacc, 16, 64);
    dacc += __shfl_xor(dacc, 32, 64);
    if (quad == 0) dLDS[grp][w * 16 + l15] = dacc;
    // group 1 exports acc partials (tile LDS is dead now; barrier above was last use)
    if (grp == 1) {
#pragma unroll
        for (int nt = 0; nt < NT; ++nt)
            *reinterpret_cast<f32x4*>(&accLDS[(t8 * NT + nt) * 4]) = acc[nt];
    }
    __syncthreads();
    if (grp == 0) {
#pragma unroll
        for (int nt = 0; nt < NT; ++nt)
            acc[nt] += *reinterpret_cast<const f32x4*>(&accLDS[(t8 * NT + nt) * 4]);
        float dinv[4];
#pragma unroll
        for (int r = 0; r < 4; ++r) {
            int row = w * 16 + quad * 4 + r;
            dinv[r] = 1.0f / fmaxf(dLDS[0][row] + dLDS[1][row], 1e-30f);
        }
        const int ib = iblk * 64 + w * 16 + quad * 4;
        if (OUT_F32) {
            float* o3 = (float*)outp;
#pragma unroll
            for (int nt = 0; nt < NT; ++nt)
#pragma unroll
                for (int r = 0; r < 4; ++r) {
                    float vv = fmaxf(acc[nt][r] * dinv[r], 0.f);   // relu
                    o3[((size_t)(b * 2048 + ib + r)) * F + nt * 16 + l15] = vv;
                }
        } else {
            u16* xo = (u16*)outp;
#pragma unroll
            for (int nt = 0; nt < NT; ++nt)
#pragma unroll
                for (int r = 0; r < 4; ++r) {
                    float vv = fmaxf(acc[nt][r] * dinv[r], 0.f);
                    xo[((size_t)(b * 2048 + ib + r)) * F + nt * 16 + l15] = f2b(vv);
                }
        }
    }
}

// ---------------- final linear stage 1: [8,131072] fp32 @ [131072,128] fp32
// grid 512, block 256; block p owns k in [p*256,(p+1)*256); writes pbuf[p][b][o].
__global__ void __launch_bounds__(256) k_lin(const float* __restrict__ o3,
                                             const float* __restrict__ Wlin,
                                             float* __restrict__ pbuf) {
    __shared__ float xc[8][256];
    __shared__ float red[8][8][128];          // [kb][b][o] = 32 KB
    const int tid = threadIdx.x;
    const int k0 = blockIdx.x * 256;
    for (int idx = tid; idx < 2048; idx += 256) {
        int bb = idx >> 8, kk = idx & 255;
        xc[bb][kk] = o3[(size_t)bb * 131072 + k0 + kk];
    }
    __syncthreads();
    const int o4 = tid & 31;                  // float4 output group: o = 4*o4..4*o4+3
    const int kb = tid >> 5;                  // k band: 32 k each
    f32x4 acc[8];
#pragma unroll
    for (int bb = 0; bb < 8; ++bb) acc[bb] = (f32x4){0.f, 0.f, 0.f, 0.f};
    const float* wp = Wlin + (size_t)(k0 + kb * 32) * 128 + o4 * 4;
#pragma unroll 4
    for (int k = 0; k < 32; ++k) {
        f32x4 wv = *reinterpret_cast<const f32x4*>(wp + (size_t)k * 128);
#pragma unroll
        for (int bb = 0; bb < 8; ++bb) acc[bb] += wv * xc[bb][kb * 32 + k];
    }
#pragma unroll
    for (int bb = 0; bb < 8; ++bb)
        *reinterpret_cast<f32x4*>(&red[kb][bb][o4 * 4]) = acc[bb];
    __syncthreads();
    // fold 8 k-bands: thread handles 4 flat outputs
    const int f = tid * 4;
    const int bb = f >> 7, o = f & 127;
    f32x4 s = (f32x4){0.f, 0.f, 0.f, 0.f};
#pragma unroll
    for (int k2 = 0; k2 < 8; ++k2) s += *reinterpret_cast<const f32x4*>(&red[k2][bb][o]);
    *reinterpret_cast<f32x4*>(&pbuf[(size_t)blockIdx.x * 1024 + f]) = s;
}

// ---------------- stage 2: fold 512 partials + bias -> out
__global__ void __launch_bounds__(128) k_bias(const float* __restrict__ pbuf,
                                              const float* __restrict__ blin,
                                              float* __restrict__ out) {
    const int f = blockIdx.x * 128 + threadIdx.x;   // grid 8 -> 1024 outputs
    float s0 = 0.f, s1 = 0.f, s2 = 0.f, s3 = 0.f;
    for (int p = 0; p < 512; p += 4) {
        s0 += pbuf[(size_t)p * 1024 + f];
        s1 += pbuf[(size_t)(p + 1) * 1024 + f];
        s2 += pbuf[(size_t)(p + 2) * 1024 + f];
        s3 += pbuf[(size_t)(p + 3) * 1024 + f];
    }
    out[f] = (s0 + s1) + (s2 + s3) + blin[f & 127];
}

extern "C" void kernel_launch(void* const* d_in, const int* in_sizes, int n_in,
                              void* d_out, int out_size, void* d_ws, size_t ws_size,
                              hipStream_t stream) {
    (void)in_sizes; (void)n_in; (void)out_size;
    const float* x    = (const float*)d_in[0];
    const float* adj  = (const float*)d_in[1];
    const float* W1   = (const float*)d_in[2];
    const float* a1s  = (const float*)d_in[3];
    const float* a1d  = (const float*)d_in[4];
    const float* W2   = (const float*)d_in[5];
    const float* a2s  = (const float*)d_in[6];
    const float* a2d  = (const float*)d_in[7];
    const float* W3   = (const float*)d_in[8];
    const float* a3s  = (const float*)d_in[9];
    const float* a3d  = (const float*)d_in[10];
    const float* Wlin = (const float*)d_in[11];
    const float* blin = (const float*)d_in[12];

    // ---- workspace layout (adaptive; never early-return) ----
    char* ws = (char*)d_ws;
    u16*   h_t = (u16*)ws;                          // 4 MB  [8][F][2048] bf16
    size_t off = (size_t)4 << 20;
    float* es2 = (float*)(ws + off); off += 65536;
    float* ed2 = (float*)(ws + off); off += 65536;
    u16*   Wt1 = (u16*)(ws + off);   off += 32768;
    u16*   Wt2 = (u16*)(ws + off);   off += 32768;
    u16*   Wt3 = (u16*)(ws + off);   off += 16384;
    float* u1s = (float*)(ws + off); off += 512;
    float* u1d = (float*)(ws + off); off += 512;
    float* u2s = (float*)(ws + off); off += 512;
    float* u2d = (float*)(ws + off); off += 512;
    float* u3s = (float*)(ws + off); off += 512;
    float* u3d = (float*)(ws + off); off += 512;
    uint32_t* adjm = (uint32_t*)(ws + off); off += 524288;    // [2048][64] bitmask
    float* pbuf = (float*)(ws + off); off += (size_t)512 * 1024 * 4;  // 2 MB partials
    // activation ping (bf16 [8][2048][128] = 4MB) aliases layer-3 fp32 out
    // ([8][2048][64] fp32 = 4MB): disjoint live ranges. Fallback: alias the x
    // input (16MB fp32; dead after layer-1 k_h; restored by harness pre-launch).
    u16* actA;
    if (ws_size >= off + ((size_t)4 << 20)) {
        actA = (u16*)(ws + off);
    } else {
        actA = (u16*)d_in[0];
    }
    float* o3 = (float*)actA;

    dim3 g(8, 32);
    k_mask<<<512, 256, 0, stream>>>(adj, adjm);
    k_prep<<<161, 256, 0, stream>>>(W1, W2, W3, a1s, a1d, a2s, a2d, a3s, a3d,
                                    Wt1, Wt2, Wt3, u1s, u1d, u2s, u2d, u3s, u3d);

    k_h<128, true ><<<g, 256, 0, stream>>>((const void*)x, Wt1, u1s, u1d, h_t, es2, ed2);
    k_attn<128, false><<<g, 512, 0, stream>>>(es2, ed2, adjm, h_t, (void*)actA);

    k_h<128, false><<<g, 256, 0, stream>>>((const void*)actA, Wt2, u2s, u2d, h_t, es2, ed2);
    k_attn<128, false><<<g, 512, 0, stream>>>(es2, ed2, adjm, h_t, (void*)actA);

    k_h<64, false><<<g, 256, 0, stream>>>((const void*)actA, Wt3, u3s, u3d, h_t, es2, ed2);
    k_attn<64, true ><<<g, 512, 0, stream>>>(es2, ed2, adjm, h_t, (void*)o3);

    k_lin<<<512, 256, 0, stream>>>(o3, Wlin, pbuf);
    k_bias<<<8, 128, 0, stream>>>(pbuf, blin, (float*)d_out);
}

// Round 6
// 259.840 us; speedup vs baseline: 1.6979x; 1.1272x over previous
//
#include <hip/hip_runtime.h>
#include <stdint.h>

// GAT 3-layer + linear head, MI355X (gfx950).
// I/O is FP32 (per reference). Internals: bf16 MFMA for h and att@h
// (softmax-averaging damps bf16 rounding); logits and final linear in fp32.
// R6: k_bias fold parallelized (64 blk x 256 thr, 16 thr/output) — was 16
// waves on the whole GPU, 41 us of pure latency.

typedef unsigned short u16;
typedef __bf16 bf16x8 __attribute__((ext_vector_type(8)));
typedef float f32x4 __attribute__((ext_vector_type(4)));
typedef u16 u16x8 __attribute__((ext_vector_type(8)));

#define LOG2E 1.44269504088896340736f

__device__ __forceinline__ float b2f(u16 u) {
    union { unsigned int i; float f; } v; v.i = ((unsigned int)u) << 16; return v.f;
}
__device__ __forceinline__ u16 f2b(float f) {   // RNE round to bf16
    union { float f; unsigned int i; } v; v.f = f;
    unsigned int i = v.i;
    return (u16)((i + 0x7fffu + ((i >> 16) & 1u)) >> 16);
}
__device__ __forceinline__ float fast_exp2(float x) {
#if __has_builtin(__builtin_amdgcn_exp2f)
    return __builtin_amdgcn_exp2f(x);
#else
    return exp2f(x);
#endif
}

union ABfrag { bf16x8 v; u16x8 u; };

__device__ __forceinline__ void gload_lds16(const u16* g, u16* l) {
    // async global->LDS, 16B/lane, LDS dest = wave-uniform base + lane*16
    __builtin_amdgcn_global_load_lds((const __attribute__((address_space(1))) void*)g,
                                     (__attribute__((address_space(3))) void*)l,
                                     16, 0, 0);
}

// ---------------- k_mask: adjacency bitmask, adjm[row][64] uint32 (bit j of row)
__global__ void __launch_bounds__(256) k_mask(const float* __restrict__ adj,
                                              uint32_t* __restrict__ adjm) {
    const int w = threadIdx.x >> 6, lane = threadIdx.x & 63;
    const int row = blockIdx.x * 4 + w;
    const float* ar = adj + (size_t)row * 2048;
    uint32_t* mr = adjm + (size_t)row * 64;
    for (int j0 = 0; j0 < 2048; j0 += 64) {
        unsigned long long m = __ballot(ar[j0 + lane] > 0.f);
        if (lane == 0) {
            mr[(j0 >> 5)] = (uint32_t)m;
            mr[(j0 >> 5) + 1] = (uint32_t)(m >> 32);
        }
    }
}

// ---------------- prep: bf16-transpose W's, u = (W @ a)*log2e (fp32)
__global__ void k_prep(const float* __restrict__ W1, const float* __restrict__ W2,
                       const float* __restrict__ W3,
                       const float* __restrict__ a1s, const float* __restrict__ a1d,
                       const float* __restrict__ a2s, const float* __restrict__ a2d,
                       const float* __restrict__ a3s, const float* __restrict__ a3d,
                       u16* __restrict__ Wt1, u16* __restrict__ Wt2, u16* __restrict__ Wt3,
                       float* __restrict__ u1s, float* __restrict__ u1d,
                       float* __restrict__ u2s, float* __restrict__ u2d,
                       float* __restrict__ u3s, float* __restrict__ u3d) {
    if (blockIdx.x == 160) {                 // u-vectors: fp32 matvecs, trivial size
        int f = threadIdx.x;
        if (f < 128) {
            float s1 = 0.f, d1 = 0.f, s2 = 0.f, d2 = 0.f, s3 = 0.f, d3 = 0.f;
            for (int o = 0; o < 128; ++o) { float w = W1[f * 128 + o]; s1 += w * a1s[o]; d1 += w * a1d[o]; }
            for (int o = 0; o < 128; ++o) { float w = W2[f * 128 + o]; s2 += w * a2s[o]; d2 += w * a2d[o]; }
            for (int o = 0; o <  64; ++o) { float w = W3[f *  64 + o]; s3 += w * a3s[o]; d3 += w * a3d[o]; }
            u1s[f] = s1 * LOG2E; u1d[f] = d1 * LOG2E;
            u2s[f] = s2 * LOG2E; u2d[f] = d2 * LOG2E;
            u3s[f] = s3 * LOG2E; u3d[f] = d3 * LOG2E;
        }
        return;
    }
    int idx = blockIdx.x * 256 + threadIdx.x;
    if (idx < 16384) {                       // W1: [128,128] -> Wt1[o][f] bf16
        int f = idx >> 7, o = idx & 127;
        Wt1[o * 128 + f] = f2b(W1[idx]);
    } else if (idx < 32768) {                // W2
        int j = idx - 16384; int f = j >> 7, o = j & 127;
        Wt2[o * 128 + f] = f2b(W2[j]);
    } else if (idx < 40960) {                // W3: [128,64] -> Wt3[o][f]
        int j = idx - 32768; int f = j >> 6, o = j & 63;
        Wt3[o * 128 + f] = f2b(W3[j]);
    }
}

// ---------------- k_h: h = act @ W (bf16 MFMA) -> h^T bf16; es/ed = act . u (fp32)
// grid (8, 32) = (b, nblk), block 256 (4 waves x 16 rows). K = 128 always.
template <int F, bool XF32>
__global__ void __launch_bounds__(256) k_h(const void* __restrict__ xv,
                                           const u16* __restrict__ Wt,
                                           const float* __restrict__ us,
                                           const float* __restrict__ ud,
                                           u16* __restrict__ h_t,
                                           float* __restrict__ es2,
                                           float* __restrict__ ed2) {
    constexpr int NT = F / 16;
    constexpr int TNP = 72;                  // padded n-stride (144B = 9x16B)
    __shared__ __align__(16) u16 hl[F * TNP];

    const int b = blockIdx.x;
    const int nblk = blockIdx.y;
    const int tid = threadIdx.x;
    const int w = tid >> 6, lane = tid & 63;
    const int quad = lane >> 4, l15 = lane & 15;
    const int n0w = nblk * 64 + w * 16;
    const int i_a = n0w + l15;               // A-operand row (m = lane&15)

    ABfrag afr[4];
    float ps = 0.f, pd = 0.f;
    if (XF32) {
        const float* xr = (const float*)xv + ((size_t)(b * 2048 + i_a)) * 128;
#pragma unroll
        for (int kk = 0; kk < 4; ++kk) {
            const int o8 = kk * 32 + quad * 8;
            float4 x0 = *reinterpret_cast<const float4*>(xr + o8);
            float4 x1 = *reinterpret_cast<const float4*>(xr + o8 + 4);
            float4 s0 = *reinterpret_cast<const float4*>(us + o8);
            float4 s1 = *reinterpret_cast<const float4*>(us + o8 + 4);
            float4 d0 = *reinterpret_cast<const float4*>(ud + o8);
            float4 d1 = *reinterpret_cast<const float4*>(ud + o8 + 4);
            ps += x0.x * s0.x + x0.y * s0.y + x0.z * s0.z + x0.w * s0.w
                + x1.x * s1.x + x1.y * s1.y + x1.z * s1.z + x1.w * s1.w;
            pd += x0.x * d0.x + x0.y * d0.y + x0.z * d0.z + x0.w * d0.w
                + x1.x * d1.x + x1.y * d1.y + x1.z * d1.z + x1.w * d1.w;
            afr[kk].u[0] = f2b(x0.x); afr[kk].u[1] = f2b(x0.y);
            afr[kk].u[2] = f2b(x0.z); afr[kk].u[3] = f2b(x0.w);
            afr[kk].u[4] = f2b(x1.x); afr[kk].u[5] = f2b(x1.y);
            afr[kk].u[6] = f2b(x1.z); afr[kk].u[7] = f2b(x1.w);
        }
    } else {
        const u16* xr = (const u16*)xv + ((size_t)(b * 2048 + i_a)) * 128;
#pragma unroll
        for (int kk = 0; kk < 4; ++kk) {
            const int o8 = kk * 32 + quad * 8;
            u16x8 xa = *reinterpret_cast<const u16x8*>(xr + o8);
            afr[kk].u = xa;
            float4 s0 = *reinterpret_cast<const float4*>(us + o8);
            float4 s1 = *reinterpret_cast<const float4*>(us + o8 + 4);
            float4 d0 = *reinterpret_cast<const float4*>(ud + o8);
            float4 d1 = *reinterpret_cast<const float4*>(ud + o8 + 4);
            float xf[8];
#pragma unroll
            for (int j = 0; j < 8; ++j) xf[j] = b2f(xa[j]);
            ps += xf[0] * s0.x + xf[1] * s0.y + xf[2] * s0.z + xf[3] * s0.w
                + xf[4] * s1.x + xf[5] * s1.y + xf[6] * s1.z + xf[7] * s1.w;
            pd += xf[0] * d0.x + xf[1] * d0.y + xf[2] * d0.z + xf[3] * d0.w
                + xf[4] * d1.x + xf[5] * d1.y + xf[6] * d1.z + xf[7] * d1.w;
        }
    }
    // reduce logit partials across the 4 quads sharing l15 (full 128-dot)
    ps += __shfl_xor(ps, 16, 64); ps += __shfl_xor(ps, 32, 64);
    pd += __shfl_xor(pd, 16, 64); pd += __shfl_xor(pd, 32, 64);
    if (quad == 0) {
        es2[b * 2048 + i_a] = ps;            // already *log2e via u pre-scale
        ed2[b * 2048 + i_a] = pd;
    }

    f32x4 acc[NT];
#pragma unroll
    for (int nt = 0; nt < NT; ++nt) acc[nt] = (f32x4){0.f, 0.f, 0.f, 0.f};
#pragma unroll
    for (int kk = 0; kk < 4; ++kk) {
#pragma unroll
        for (int nt = 0; nt < NT; ++nt) {
            bf16x8 bfv = *reinterpret_cast<const bf16x8*>(
                Wt + (nt * 16 + l15) * 128 + kk * 32 + quad * 8);
            acc[nt] = __builtin_amdgcn_mfma_f32_16x16x32_bf16(afr[kk].v, bfv, acc[nt], 0, 0, 0);
        }
    }

    // stage transposed tile to LDS (D: col=l15 -> o, row=quad*4+r -> i), then
    // coalesced global write of h^T[b][o][n]
#pragma unroll
    for (int nt = 0; nt < NT; ++nt)
#pragma unroll
        for (int r = 0; r < 4; ++r)
            hl[(nt * 16 + l15) * TNP + w * 16 + quad * 4 + r] = f2b(acc[nt][r]);
    __syncthreads();
    if (tid < F * 2) {
        int o = tid >> 1, half = tid & 1;
        const u16* src = hl + o * TNP + half * 32;
        u16* dst = h_t + ((size_t)(b * F + o)) * 2048 + nblk * 64 + half * 32;
#pragma unroll
        for (int c = 0; c < 4; ++c)
            *reinterpret_cast<u16x8*>(dst + c * 8) =
                *reinterpret_cast<const u16x8*>(src + c * 8);
    }
}

// ---------------- k_attn: fused masked-softmax(P) @ H, software-pipelined MFMA.
// grid (8, 32) = (b, iblk), block 512 = 2 j-groups x 4 waves x 16 i-rows.
// Each group sweeps half the j range with its own double-buffered LDS tiles;
// partial acc + denom combined through LDS at the end.
template <int F, bool OUT_F32>
__global__ void __launch_bounds__(512) k_attn(const float* __restrict__ es2,
                                              const float* __restrict__ ed2,
                                              const uint32_t* __restrict__ adjm,
                                              const u16* __restrict__ h_t,
                                              void* __restrict__ outp) {
    constexpr int NT = F / 16;
    __shared__ __align__(16) u16 Ht[2][2][F * 64];  // [grp][buf], xor-swizzled chunks
    __shared__ float dLDS[2][64];
    float* accLDS = (float*)&Ht[0][0][0];           // combine area (aliases tiles, used after)

    const int b = blockIdx.x;
    const int iblk = blockIdx.y;
    const int tid = threadIdx.x;
    const int grp = tid >> 8;                 // j-group 0/1
    const int t8 = tid & 255;
    const int w = t8 >> 6;                    // wave-within-group
    const int lane = tid & 63;
    const int quad = lane >> 4, l15 = lane & 15;
    const int i_a = iblk * 64 + w * 16 + l15;

    const float esv = es2[b * 2048 + i_a];
    const float* edb = ed2 + b * 2048;
    const uint2* mrow = (const uint2*)(adjm + (size_t)i_a * 64);
    const u16* hb = h_t + (size_t)b * F * 2048;

    const int lro = lane >> 3;
    const int lcp = lane & 7;
    const int jt0 = grp * 16;                 // this group's jt range [jt0, jt0+16)

    f32x4 acc[NT];
#pragma unroll
    for (int nt = 0; nt < NT; ++nt) acc[nt] = (f32x4){0.f, 0.f, 0.f, 0.f};
    float dacc = 0.f;

    // ---- prologue: stage this group's tile 0 + prefetch regs
    {
        const int j0 = jt0 * 64;
#pragma unroll
        for (int it = 0; it < F / 32; ++it) {
            int ro = (it * 4 + w) * 8 + lro;
            int c = lcp ^ (ro & 7);
            gload_lds16(hb + (size_t)ro * 2048 + j0 + c * 8, &Ht[grp][0][(it * 4 + w) * 512]);
        }
    }
    float4 ec0 = *reinterpret_cast<const float4*>(edb + jt0 * 64 + quad * 8);
    float4 ec1 = *reinterpret_cast<const float4*>(edb + jt0 * 64 + quad * 8 + 4);
    float4 ec2 = *reinterpret_cast<const float4*>(edb + jt0 * 64 + quad * 8 + 32);
    float4 ec3 = *reinterpret_cast<const float4*>(edb + jt0 * 64 + quad * 8 + 36);
    uint2 mc = mrow[jt0];
    __syncthreads();                          // both groups' tile 0 staged

    for (int jj = 0; jj < 16; ++jj) {
        const int cur = jj & 1, nxt = cur ^ 1;
        float4 en0, en1, en2, en3; uint2 mn;
        if (jj < 15) {
            const int j1 = (jt0 + jj + 1) * 64;
#pragma unroll
            for (int it = 0; it < F / 32; ++it) {
                int ro = (it * 4 + w) * 8 + lro;
                int c = lcp ^ (ro & 7);
                gload_lds16(hb + (size_t)ro * 2048 + j1 + c * 8, &Ht[grp][nxt][(it * 4 + w) * 512]);
            }
            en0 = *reinterpret_cast<const float4*>(edb + j1 + quad * 8);
            en1 = *reinterpret_cast<const float4*>(edb + j1 + quad * 8 + 4);
            en2 = *reinterpret_cast<const float4*>(edb + j1 + quad * 8 + 32);
            en3 = *reinterpret_cast<const float4*>(edb + j1 + quad * 8 + 36);
            mn = mrow[jt0 + jj + 1];
        }

        // P fragments in A-operand layout from current regs
        ABfrag af[2];
        {
            float ed[16] = {ec0.x, ec0.y, ec0.z, ec0.w, ec1.x, ec1.y, ec1.z, ec1.w,
                            ec2.x, ec2.y, ec2.z, ec2.w, ec3.x, ec3.y, ec3.z, ec3.w};
#pragma unroll
            for (int kk = 0; kk < 2; ++kk) {
                uint32_t word = kk ? mc.y : mc.x;
#pragma unroll
                for (int jx = 0; jx < 8; ++jx) {
                    float e = esv + ed[kk * 8 + jx];      // already *log2e
                    float v = fmaxf(e, 0.2f * e);         // leaky_relu (scale-commutes)
                    float wv = fast_exp2(v);
                    bool bit = (word >> (quad * 8 + jx)) & 1u;
                    wv = bit ? wv : 0.f;
                    u16 wb = f2b(wv);
                    af[kk].u[jx] = wb;
                    dacc += b2f(wb);                      // denom consistent with rounded P
                }
            }
        }

        // MFMA over current LDS tile
#pragma unroll
        for (int kk = 0; kk < 2; ++kk) {
#pragma unroll
            for (int nt = 0; nt < NT; ++nt) {
                int ob = nt * 16 + l15;
                int c = kk * 4 + quad;
                bf16x8 bfv = *reinterpret_cast<const bf16x8*>(
                    &Ht[grp][cur][ob * 64 + ((c ^ (ob & 7)) * 8)]);
                acc[nt] = __builtin_amdgcn_mfma_f32_16x16x32_bf16(af[kk].v, bfv, acc[nt], 0, 0, 0);
            }
        }

        if (jj < 15) { ec0 = en0; ec1 = en1; ec2 = en2; ec3 = en3; mc = mn; }
        __syncthreads();   // drains next-tile staging; cur consumed before overwrite
    }

    // group-partial denom: reduce over quads -> every lane holds its row's partial
    dacc += __shfl_xor(dacc, 16, 64);
    dacc += __shfl_xor(dacc, 32, 64);
    if (quad == 0) dLDS[grp][w * 16 + l15] = dacc;
    // group 1 exports acc partials (tile LDS is dead now; barrier above was last use)
    if (grp == 1) {
#pragma unroll
        for (int nt = 0; nt < NT; ++nt)
            *reinterpret_cast<f32x4*>(&accLDS[(t8 * NT + nt) * 4]) = acc[nt];
    }
    __syncthreads();
    if (grp == 0) {
#pragma unroll
        for (int nt = 0; nt < NT; ++nt)
            acc[nt] += *reinterpret_cast<const f32x4*>(&accLDS[(t8 * NT + nt) * 4]);
        float dinv[4];
#pragma unroll
        for (int r = 0; r < 4; ++r) {
            int row = w * 16 + quad * 4 + r;
            dinv[r] = 1.0f / fmaxf(dLDS[0][row] + dLDS[1][row], 1e-30f);
        }
        const int ib = iblk * 64 + w * 16 + quad * 4;
        if (OUT_F32) {
            float* o3 = (float*)outp;
#pragma unroll
            for (int nt = 0; nt < NT; ++nt)
#pragma unroll
                for (int r = 0; r < 4; ++r) {
                    float vv = fmaxf(acc[nt][r] * dinv[r], 0.f);   // relu
                    o3[((size_t)(b * 2048 + ib + r)) * F + nt * 16 + l15] = vv;
                }
        } else {
            u16* xo = (u16*)outp;
#pragma unroll
            for (int nt = 0; nt < NT; ++nt)
#pragma unroll
                for (int r = 0; r < 4; ++r) {
                    float vv = fmaxf(acc[nt][r] * dinv[r], 0.f);
                    xo[((size_t)(b * 2048 + ib + r)) * F + nt * 16 + l15] = f2b(vv);
                }
        }
    }
}

// ---------------- final linear stage 1: [8,131072] fp32 @ [131072,128] fp32
// grid 512, block 256; block p owns k in [p*256,(p+1)*256); writes pbuf[p][b][o].
__global__ void __launch_bounds__(256) k_lin(const float* __restrict__ o3,
                                             const float* __restrict__ Wlin,
                                             float* __restrict__ pbuf) {
    __shared__ float xc[8][256];
    __shared__ float red[8][8][128];          // [kb][b][o] = 32 KB
    const int tid = threadIdx.x;
    const int k0 = blockIdx.x * 256;
    for (int idx = tid; idx < 2048; idx += 256) {
        int bb = idx >> 8, kk = idx & 255;
        xc[bb][kk] = o3[(size_t)bb * 131072 + k0 + kk];
    }
    __syncthreads();
    const int o4 = tid & 31;                  // float4 output group: o = 4*o4..4*o4+3
    const int kb = tid >> 5;                  // k band: 32 k each
    f32x4 acc[8];
#pragma unroll
    for (int bb = 0; bb < 8; ++bb) acc[bb] = (f32x4){0.f, 0.f, 0.f, 0.f};
    const float* wp = Wlin + (size_t)(k0 + kb * 32) * 128 + o4 * 4;
#pragma unroll 4
    for (int k = 0; k < 32; ++k) {
        f32x4 wv = *reinterpret_cast<const f32x4*>(wp + (size_t)k * 128);
#pragma unroll
        for (int bb = 0; bb < 8; ++bb) acc[bb] += wv * xc[bb][kb * 32 + k];
    }
#pragma unroll
    for (int bb = 0; bb < 8; ++bb)
        *reinterpret_cast<f32x4*>(&red[kb][bb][o4 * 4]) = acc[bb];
    __syncthreads();
    // fold 8 k-bands: thread handles 4 flat outputs
    const int f = tid * 4;
    const int bb = f >> 7, o = f & 127;
    f32x4 s = (f32x4){0.f, 0.f, 0.f, 0.f};
#pragma unroll
    for (int k2 = 0; k2 < 8; ++k2) s += *reinterpret_cast<const f32x4*>(&red[k2][bb][o]);
    *reinterpret_cast<f32x4*>(&pbuf[(size_t)blockIdx.x * 1024 + f]) = s;
}

// ---------------- stage 2: fold 512 partials + bias -> out
// grid 64 x 256: block owns 16 outputs; 16 threads/output sum strided partials.
__global__ void __launch_bounds__(256) k_bias(const float* __restrict__ pbuf,
                                              const float* __restrict__ blin,
                                              float* __restrict__ out) {
    __shared__ float red[256];
    const int tid = threadIdx.x;
    const int p16 = tid >> 4;                 // 16 p-groups
    const int fo = tid & 15;
    const int f0 = blockIdx.x * 16;
    float s = 0.f;
#pragma unroll 4
    for (int p = p16; p < 512; p += 16)
        s += pbuf[(size_t)p * 1024 + f0 + fo];
    red[tid] = s;
    __syncthreads();
    if (tid < 16) {
        float t = 0.f;
#pragma unroll
        for (int k = 0; k < 16; ++k) t += red[k * 16 + tid];
        out[f0 + tid] = t + blin[(f0 + tid) & 127];
    }
}

extern "C" void kernel_launch(void* const* d_in, const int* in_sizes, int n_in,
                              void* d_out, int out_size, void* d_ws, size_t ws_size,
                              hipStream_t stream) {
    (void)in_sizes; (void)n_in; (void)out_size;
    const float* x    = (const float*)d_in[0];
    const float* adj  = (const float*)d_in[1];
    const float* W1   = (const float*)d_in[2];
    const float* a1s  = (const float*)d_in[3];
    const float* a1d  = (const float*)d_in[4];
    const float* W2   = (const float*)d_in[5];
    const float* a2s  = (const float*)d_in[6];
    const float* a2d  = (const float*)d_in[7];
    const float* W3   = (const float*)d_in[8];
    const float* a3s  = (const float*)d_in[9];
    const float* a3d  = (const float*)d_in[10];
    const float* Wlin = (const float*)d_in[11];
    const float* blin = (const float*)d_in[12];

    // ---- workspace layout (adaptive; never early-return) ----
    char* ws = (char*)d_ws;
    u16*   h_t = (u16*)ws;                          // 4 MB  [8][F][2048] bf16
    size_t off = (size_t)4 << 20;
    float* es2 = (float*)(ws + off); off += 65536;
    float* ed2 = (float*)(ws + off); off += 65536;
    u16*   Wt1 = (u16*)(ws + off);   off += 32768;
    u16*   Wt2 = (u16*)(ws + off);   off += 32768;
    u16*   Wt3 = (u16*)(ws + off);   off += 16384;
    float* u1s = (float*)(ws + off); off += 512;
    float* u1d = (float*)(ws + off); off += 512;
    float* u2s = (float*)(ws + off); off += 512;
    float* u2d = (float*)(ws + off); off += 512;
    float* u3s = (float*)(ws + off); off += 512;
    float* u3d = (float*)(ws + off); off += 512;
    uint32_t* adjm = (uint32_t*)(ws + off); off += 524288;    // [2048][64] bitmask
    float* pbuf = (float*)(ws + off); off += (size_t)512 * 1024 * 4;  // 2 MB partials
    // activation ping (bf16 [8][2048][128] = 4MB) aliases layer-3 fp32 out
    // ([8][2048][64] fp32 = 4MB): disjoint live ranges. Fallback: alias the x
    // input (16MB fp32; dead after layer-1 k_h; restored by harness pre-launch).
    u16* actA;
    if (ws_size >= off + ((size_t)4 << 20)) {
        actA = (u16*)(ws + off);
    } else {
        actA = (u16*)d_in[0];
    }
    float* o3 = (float*)actA;

    dim3 g(8, 32);
    k_mask<<<512, 256, 0, stream>>>(adj, adjm);
    k_prep<<<161, 256, 0, stream>>>(W1, W2, W3, a1s, a1d, a2s, a2d, a3s, a3d,
                                    Wt1, Wt2, Wt3, u1s, u1d, u2s, u2d, u3s, u3d);

    k_h<128, true ><<<g, 256, 0, stream>>>((const void*)x, Wt1, u1s, u1d, h_t, es2, ed2);
    k_attn<128, false><<<g, 512, 0, stream>>>(es2, ed2, adjm, h_t, (void*)actA);

    k_h<128, false><<<g, 256, 0, stream>>>((const void*)actA, Wt2, u2s, u2d, h_t, es2, ed2);
    k_attn<128, false><<<g, 512, 0, stream>>>(es2, ed2, adjm, h_t, (void*)actA);

    k_h<64, false><<<g, 256, 0, stream>>>((const void*)actA, Wt3, u3s, u3d, h_t, es2, ed2);
    k_attn<64, true ><<<g, 512, 0, stream>>>(es2, ed2, adjm, h_t, (void*)o3);

    k_lin<<<512, 256, 0, stream>>>(o3, Wlin, pbuf);
    k_bias<<<64, 256, 0, stream>>>(pbuf, blin, (float*)d_out);
}